// Round 3
// baseline (176.740 us; speedup 1.0000x reference)
//
#include <hip/hip_runtime.h>

#define DIRECTIONAL_PENALTY 1.5f
#define CONFIDENCE_WEIGHT 0.1f

// Per-row loss contribution. 3 logits a,b,c; target t; class weights w0..w2.
__device__ __forceinline__ float row_loss(float a, float b, float c, int t,
                                          float w0, float w1, float w2) {
    // argmax, first-max tie semantics (strict >)
    int pred = 0;
    float m = a;
    if (b > m) { m = b; pred = 1; }
    if (c > m) { m = c; pred = 2; }

    float e0 = __expf(a - m);
    float e1 = __expf(b - m);
    float e2 = __expf(c - m);
    float s = e0 + e1 + e2;
    float inv_s = 1.0f / s;

    float et = (t == 0) ? e0 : ((t == 1) ? e1 : e2);
    float lt = (t == 0) ? a  : ((t == 1) ? b  : c);
    float p_t = et * inv_s;
    float ce = (m - lt) + __logf(s);   // -log_softmax[target]

    float w  = (t == 0) ? w0 : ((t == 1) ? w1 : w2);
    float omp = 1.0f - p_t;
    float contrib = w * omp * omp * ce;               // focal term

    // penalty matrix is Toeplitz in |pred-t|: 0->0, 1->0.5, 2->1.5
    int d = pred - t; d = (d < 0) ? -d : d;
    float pen = (d == 1) ? 0.5f : ((d == 2) ? 1.5f : 0.0f);
    contrib += DIRECTIONAL_PENALTY * pen;

    // confidence: (1-correct) * max_prob; max_prob = exp(m-m)/s = 1/s
    if (pred != t) contrib += CONFIDENCE_WEIGHT * inv_s;
    return contrib;
}

// Tile = 1024 rows = 3072 floats = 768 float4 = 12 KB LDS.
// Thread t owns tile rows 4t..4t+3: LDS reads are 3x ds_read_b128 (48 B
// contiguous per lane; base bank 12*lane mod 32 -> all-bank perfect packing,
// conflict-free), targets are one coalesced int4.
__global__ __launch_bounds__(256) void tsl_partial(
    const float* __restrict__ logits,    // [B,3]
    const int*   __restrict__ targets,   // [B]
    const float* __restrict__ cw,        // [3]
    float*       __restrict__ partial,   // [gridDim.x]
    int nTiles, int B)
{
    __shared__ __align__(16) float smem[3072];
    const float w0 = cw[0], w1 = cw[1], w2 = cw[2];
    const int tid = threadIdx.x;

    const int4* __restrict__ tgAll4 = (const int4*)targets;
    float acc = 0.0f;

    for (int tile = blockIdx.x; tile < nTiles; tile += gridDim.x) {
        // coalesced global -> LDS stage: 3 x dwordx4 per thread
        const float4* __restrict__ g4 = (const float4*)logits + (size_t)tile * 768;
        float4* s4 = (float4*)smem;
        s4[tid]       = g4[tid];
        s4[tid + 256] = g4[tid + 256];
        s4[tid + 512] = g4[tid + 512];

        // one coalesced int4 = targets for this thread's 4 rows
        int4 tg = tgAll4[tile * 256 + tid];
        __syncthreads();

        // rows 4*tid .. 4*tid+3 = 12 consecutive floats = 3 float4
        float4 f0 = s4[3 * tid + 0];   // r0.a r0.b r0.c r1.a
        float4 f1 = s4[3 * tid + 1];   // r1.b r1.c r2.a r2.b
        float4 f2 = s4[3 * tid + 2];   // r2.c r3.a r3.b r3.c

        acc += row_loss(f0.x, f0.y, f0.z, tg.x, w0, w1, w2);
        acc += row_loss(f0.w, f1.x, f1.y, tg.y, w0, w1, w2);
        acc += row_loss(f1.z, f1.w, f2.x, tg.z, w0, w1, w2);
        acc += row_loss(f2.y, f2.z, f2.w, tg.w, w0, w1, w2);

        __syncthreads();   // before next tile overwrites smem
    }

    // remainder rows (none at B=8388608, kept for generality)
    for (int r = nTiles * 1024 + blockIdx.x * 256 + tid; r < B;
         r += gridDim.x * 256) {
        float a = logits[3 * r + 0];
        float b = logits[3 * r + 1];
        float c = logits[3 * r + 2];
        acc += row_loss(a, b, c, targets[r], w0, w1, w2);
    }

    // wave64 shuffle reduction
    #pragma unroll
    for (int off = 32; off > 0; off >>= 1)
        acc += __shfl_down(acc, off, 64);

    __shared__ float sdata[4];
    const int lane = tid & 63;
    const int wid  = tid >> 6;
    if (lane == 0) sdata[wid] = acc;
    __syncthreads();
    if (tid == 0)
        partial[blockIdx.x] = sdata[0] + sdata[1] + sdata[2] + sdata[3];
}

__global__ __launch_bounds__(256) void tsl_final(
    const float* __restrict__ partial, int n,
    float* __restrict__ out, float inv_b)
{
    float acc = 0.0f;
    for (int i = threadIdx.x; i < n; i += 256) acc += partial[i];

    #pragma unroll
    for (int off = 32; off > 0; off >>= 1)
        acc += __shfl_down(acc, off, 64);

    __shared__ float sdata[4];
    const int lane = threadIdx.x & 63;
    const int wid  = threadIdx.x >> 6;
    if (lane == 0) sdata[wid] = acc;
    __syncthreads();
    if (threadIdx.x == 0)
        out[0] = (sdata[0] + sdata[1] + sdata[2] + sdata[3]) * inv_b;
}

extern "C" void kernel_launch(void* const* d_in, const int* in_sizes, int n_in,
                              void* d_out, int out_size, void* d_ws, size_t ws_size,
                              hipStream_t stream) {
    const float* logits  = (const float*)d_in[0];
    const int*   targets = (const int*)d_in[1];
    const float* cw      = (const float*)d_in[2];
    float* out     = (float*)d_out;
    float* partial = (float*)d_ws;         // 2048 floats, fully overwritten

    const int B = in_sizes[1];             // 8388608
    const int nTiles = B / 1024;           // 8192
    const float inv_b = 1.0f / (float)B;

    const int blocks = 2048;               // 4 tiles/block, 8 blocks/CU
    tsl_partial<<<blocks, 256, 0, stream>>>(logits, targets, cw, partial, nTiles, B);
    tsl_final<<<1, 256, 0, stream>>>(partial, blocks, out, inv_b);
}